// Round 8
// baseline (1741.899 us; speedup 1.0000x reference)
//
#include <hip/hip_runtime.h>
#include <hip/hip_bf16.h>

#define N_NODES 50000
#define N_EDGES 800000
#define CH 128
#define ED 64
#define NG 8          // nodes per block in k_aggmm
#define TR 64         // edge slots per MFMA tile
#define GSTRIDE 65    // GT row stride (floats)
#define BM 64         // k_mlp M-tile
#define BK 32         // k_mlp K-chunk
#define LDA (BM + 4)
#define SCAN_BS 512

typedef short v8s __attribute__((ext_vector_type(8)));   // 8 bf16 bit-patterns (4 VGPRs)
typedef float v4f __attribute__((ext_vector_type(4)));

__device__ __forceinline__ unsigned short rne_bf16(float f) {
    unsigned u = __float_as_uint(f);
    return (unsigned short)((u + 0x7FFFu + ((u >> 16) & 1u)) >> 16);
}
__device__ __forceinline__ float bf16_to_f(unsigned short h) {
    return __uint_as_float((unsigned)h << 16);
}

// ---------------- CSR build ----------------

__global__ void k_hist(const int* __restrict__ dst, int* __restrict__ deg, int E) {
    int e = blockIdx.x * blockDim.x + threadIdx.x;
    if (e < E) atomicAdd(&deg[dst[e]], 1);
}

__global__ void k_scan1(const int* __restrict__ deg, int* __restrict__ blkTot, int n) {
    __shared__ int s[SCAN_BS];
    int tid = threadIdx.x;
    int i = blockIdx.x * SCAN_BS + tid;
    s[tid] = (i < n) ? deg[i] : 0;
    __syncthreads();
    for (int st = SCAN_BS / 2; st > 0; st >>= 1) {
        if (tid < st) s[tid] += s[tid + st];
        __syncthreads();
    }
    if (tid == 0) blkTot[blockIdx.x] = s[0];
}

__global__ void k_scan2(const int* __restrict__ blkTot, int* __restrict__ blkOff, int nblk) {
    __shared__ int s[128];
    int tid = threadIdx.x;
    int v = (tid < nblk) ? blkTot[tid] : 0;
    s[tid] = v;
    __syncthreads();
    for (int st = 1; st < 128; st <<= 1) {
        int t = (tid >= st) ? s[tid - st] : 0;
        __syncthreads();
        s[tid] += t;
        __syncthreads();
    }
    if (tid < nblk) blkOff[tid] = s[tid] - v;  // exclusive
}

__global__ void k_scan3(const int* __restrict__ deg, const int* __restrict__ blkOff,
                        int* __restrict__ offs, int* __restrict__ cursor, int n, int E) {
    __shared__ int s[SCAN_BS];
    int tid = threadIdx.x;
    int i = blockIdx.x * SCAN_BS + tid;
    int v = (i < n) ? deg[i] : 0;
    s[tid] = v;
    __syncthreads();
    for (int st = 1; st < SCAN_BS; st <<= 1) {
        int t = (tid >= st) ? s[tid - st] : 0;
        __syncthreads();
        s[tid] += t;
        __syncthreads();
    }
    int excl = s[tid] - v + blkOff[blockIdx.x];
    if (i < n) { offs[i] = excl; cursor[i] = excl; }
    if (i == 0) offs[n] = E;
}

__global__ void k_scatter(const int* __restrict__ adj, int* __restrict__ cursor,
                          int* __restrict__ slot_eid, int E) {
    int e = blockIdx.x * blockDim.x + threadIdx.x;
    if (e >= E) return;
    int d = adj[E + e];
    int pos = atomicAdd(&cursor[d], 1);
    slot_eid[pos] = e;
}

// ---------------- MFMA edge-GEMM + fused segmented aggregation ----------------
// Per block: NG=8 nodes, their CSR slots in 64-edge tiles.
// MFMA (short8 bf16 frags, hi/lo split: AhBh+AlBh+AhBl): G = EV @ W -> GT[ch][slot] in LDS.
// Scan: relu(G + x[src] + eb) segment-summed into zacc via direct node-transition checks.
// z[n] = (1+eps)*x[n] + zacc[n].
__global__ __launch_bounds__(256, 2) void k_aggmm(
    const float* __restrict__ x,          // [N][128]
    const float* __restrict__ ev,         // [E][64]
    const int* __restrict__ offs,
    const int* __restrict__ slot_eid,
    const int* __restrict__ adj,          // [2][E]: src row then dst row
    const float* __restrict__ Wk,         // [64][128]
    const float* __restrict__ ebk,        // [128]
    const float* __restrict__ epsk,
    float* __restrict__ z)                // [N][128]
{
    __shared__ float GT[CH][GSTRIDE];     // 33.3 KB
    __shared__ float zacc[NG][CH];        // 4 KB
    __shared__ int eid_s[TR], src_s[TR], nod_s[TR];

    const int tid = threadIdx.x;
    const int lane = tid & 63;
    const int w = tid >> 6;               // wave 0..3
    const int base_n = blockIdx.x * NG;
    const int beg = offs[base_n];
    const int end = offs[base_n + NG];
    const int nt = (end - beg + TR - 1) / TR;

    // ---- B fragments: W hi/lo bf16 bit-patterns, loaded once, all tiles ----
    // B[k][col]: col = (lane&15) + 16*ct, k = kk*32 + (lane>>4)*8 + i  (same k-map as A)
    const int bcol = lane & 15;
    const int bg = lane >> 4;
    v8s bh[8][2], bl[8][2];
#pragma unroll
    for (int ct = 0; ct < 8; ct++)
#pragma unroll
        for (int kk = 0; kk < 2; kk++)
#pragma unroll
            for (int i = 0; i < 8; i++) {
                float wv = Wk[(size_t)(kk * 32 + bg * 8 + i) * CH + ct * 16 + bcol];
                unsigned short h = rne_bf16(wv);
                bh[ct][kk][i] = (short)h;
                bl[ct][kk][i] = (short)rne_bf16(wv - bf16_to_f(h));
            }

    // zero zacc
#pragma unroll
    for (int i = 0; i < 4; i++) ((float*)zacc)[i * 256 + tid] = 0.f;

    const int c = tid & 127;
    const float ebc = ebk[c];

    for (int t = 0; t < nt; t++) {
        const int ts = beg + t * TR;
        const int m = min(TR, end - ts);

        // ---- stage slot metadata (wave 0); src/dst re-derived from adj ----
        if (tid < 64) {
            int idx = ts + (tid < m ? tid : 0);
            int e_ = slot_eid[idx];
            eid_s[tid] = e_;
            src_s[tid] = adj[e_];
            nod_s[tid] = adj[N_EDGES + e_] - base_n;
        }
        __syncthreads();

        // ---- MFMA: wave w computes rows 16w..16w+15 of G (16x64 @ 64x128) ----
        {
            const int arow = (w << 4) + (lane & 15);
            const int ag = lane >> 4;
            const int eid = eid_s[arow];
            const float* ep = ev + (size_t)eid * ED + ag * 8;
            float f0[8], f1[8];
            *(float4*)(f0)     = *(const float4*)(ep);
            *(float4*)(f0 + 4) = *(const float4*)(ep + 4);
            *(float4*)(f1)     = *(const float4*)(ep + 32);
            *(float4*)(f1 + 4) = *(const float4*)(ep + 36);
            v8s ah0, al0, ah1, al1;
#pragma unroll
            for (int i = 0; i < 8; i++) {
                unsigned short h0 = rne_bf16(f0[i]);
                ah0[i] = (short)h0;
                al0[i] = (short)rne_bf16(f0[i] - bf16_to_f(h0));
                unsigned short h1 = rne_bf16(f1[i]);
                ah1[i] = (short)h1;
                al1[i] = (short)rne_bf16(f1[i] - bf16_to_f(h1));
            }
#pragma unroll
            for (int ct = 0; ct < 8; ct++) {
                v4f a = {0.f, 0.f, 0.f, 0.f};
                a = __builtin_amdgcn_mfma_f32_16x16x32_bf16(ah0, bh[ct][0], a, 0, 0, 0);
                a = __builtin_amdgcn_mfma_f32_16x16x32_bf16(al0, bh[ct][0], a, 0, 0, 0);
                a = __builtin_amdgcn_mfma_f32_16x16x32_bf16(ah0, bl[ct][0], a, 0, 0, 0);
                a = __builtin_amdgcn_mfma_f32_16x16x32_bf16(ah1, bh[ct][1], a, 0, 0, 0);
                a = __builtin_amdgcn_mfma_f32_16x16x32_bf16(al1, bh[ct][1], a, 0, 0, 0);
                a = __builtin_amdgcn_mfma_f32_16x16x32_bf16(ah1, bl[ct][1], a, 0, 0, 0);
                // D (m89-verified): col = lane&15, row = (lane>>4)*4 + r
                const int drow = (w << 4) + ((lane >> 4) << 2);
                const int dcol = ct * 16 + (lane & 15);
#pragma unroll
                for (int r = 0; r < 4; r++) GT[dcol][drow + r] = a[r];
            }
        }
        __syncthreads();

        // ---- scan: 2 halves x 128 channels; segmented sum, direct transitions ----
        {
            const int hh = tid >> 7;
            const int j0 = hh * 32;
            const int jend = min(m, j0 + 32);
            float xv[32];
#pragma unroll
            for (int i = 0; i < 32; i++) {
                int j = j0 + i;
                xv[i] = (j < jend) ? x[(size_t)src_s[j] * CH + c] : 0.f;
            }
            float a = 0.f;
#pragma unroll
            for (int i = 0; i < 32; i++) {
                int j = j0 + i;
                if (j < jend) {
                    float v = GT[c][j] + xv[i] + ebc;
                    a += fmaxf(v, 0.f);
                    bool fl = (j + 1 >= jend) || (nod_s[j + 1] != nod_s[j]);
                    if (fl) { atomicAdd(&zacc[nod_s[j]][c], a); a = 0.f; }
                }
            }
        }
        __syncthreads();
    }

    // ---- epilogue: z = (1+eps)*x + agg ----
    const float ep1 = 1.f + *epsk;
#pragma unroll
    for (int rep = 0; rep < 4; rep++) {
        int idx = rep * 256 + tid;
        int ln = idx >> 7, cc = idx & 127;
        size_t o = (size_t)(base_n + ln) * CH + cc;
        z[o] = ep1 * x[o] + zacc[ln][cc];
    }
}

// ---------------- fused MLP: x = relu(LN(relu(BN(z@W1+b1)) @ W2 + b2)) ----------------
__global__ __launch_bounds__(256) void k_mlp(
    const float* __restrict__ zin,
    const float* __restrict__ W1, const float* __restrict__ b1,
    const float* __restrict__ bng, const float* __restrict__ bnb,
    const float* __restrict__ bnm, const float* __restrict__ bnv,
    const float* __restrict__ W2, const float* __restrict__ b2,
    const float* __restrict__ lng, const float* __restrict__ lnb,
    float* __restrict__ xout)
{
    __shared__ float Bs[BK][CH];
    __shared__ float HsT[CH][LDA];
    __shared__ float AsRed[BK * LDA];

    const int tid = threadIdx.x;
    const int tx = tid & 15, ty = tid >> 4;
    const int c0 = tx * 8, r0 = ty * 4;
    const int rb = blockIdx.x * BM;
    float acc[4][8] = {};

    for (int kb = 0; kb < CH; kb += BK) {
#pragma unroll
        for (int i = 0; i < 2; i++) {
            int idx = tid + i * 256;
            int r = idx >> 3, kq = idx & 7;
            int row = rb + r;
            float4 g = make_float4(0.f, 0.f, 0.f, 0.f);
            if (row < N_NODES) g = *(const float4*)(zin + (size_t)row * CH + kb + kq * 4);
            AsRed[(kq * 4 + 0) * LDA + r] = g.x;
            AsRed[(kq * 4 + 1) * LDA + r] = g.y;
            AsRed[(kq * 4 + 2) * LDA + r] = g.z;
            AsRed[(kq * 4 + 3) * LDA + r] = g.w;
        }
#pragma unroll
        for (int i = 0; i < 4; i++) {
            int idx = tid + i * 256;
            int k = idx >> 5, cq = idx & 31;
            *(float4*)(&Bs[k][cq * 4]) = *(const float4*)(W1 + (size_t)(kb + k) * CH + cq * 4);
        }
        __syncthreads();
#pragma unroll
        for (int k = 0; k < BK; k++) {
            float a[4], b[8];
            *(float4*)a = *(const float4*)(&AsRed[k * LDA + r0]);
            *(float4*)b = *(const float4*)(&Bs[k][c0]);
            *(float4*)(b + 4) = *(const float4*)(&Bs[k][c0 + 4]);
#pragma unroll
            for (int i = 0; i < 4; i++)
#pragma unroll
                for (int j = 0; j < 8; j++) acc[i][j] = fmaf(a[i], b[j], acc[i][j]);
        }
        __syncthreads();
    }

    {
        float sc[8], sh[8], bb[8];
#pragma unroll
        for (int j = 0; j < 8; j++) {
            int cc = c0 + j;
            float s = bng[cc] * rsqrtf(bnv[cc] + 1e-5f);
            sc[j] = s; sh[j] = bnb[cc] - bnm[cc] * s; bb[j] = b1[cc];
        }
#pragma unroll
        for (int i = 0; i < 4; i++)
#pragma unroll
            for (int j = 0; j < 8; j++) {
                float v = (acc[i][j] + bb[j]) * sc[j] + sh[j];
                HsT[c0 + j][r0 + i] = v > 0.f ? v : 0.f;
            }
    }
    __syncthreads();

    float acc2[4][8] = {};
    for (int kb = 0; kb < CH; kb += BK) {
#pragma unroll
        for (int i = 0; i < 4; i++) {
            int idx = tid + i * 256;
            int k = idx >> 5, cq = idx & 31;
            *(float4*)(&Bs[k][cq * 4]) = *(const float4*)(W2 + (size_t)(kb + k) * CH + cq * 4);
        }
        __syncthreads();
#pragma unroll
        for (int k = 0; k < BK; k++) {
            float a[4], b[8];
            *(float4*)a = *(const float4*)(&HsT[kb + k][r0]);
            *(float4*)b = *(const float4*)(&Bs[k][c0]);
            *(float4*)(b + 4) = *(const float4*)(&Bs[k][c0 + 4]);
#pragma unroll
            for (int i = 0; i < 4; i++)
#pragma unroll
                for (int j = 0; j < 8; j++) acc2[i][j] = fmaf(a[i], b[j], acc2[i][j]);
        }
        __syncthreads();
    }

    float bb[8];
#pragma unroll
    for (int j = 0; j < 8; j++) bb[j] = b2[c0 + j];
    float vals[4][8];
#pragma unroll
    for (int i = 0; i < 4; i++) {
        float s1 = 0.f, s2 = 0.f;
#pragma unroll
        for (int j = 0; j < 8; j++) {
            float v = acc2[i][j] + bb[j];
            vals[i][j] = v;
            s1 += v; s2 += v * v;
        }
        AsRed[((r0 + i) * 16 + tx) * 2 + 0] = s1;
        AsRed[((r0 + i) * 16 + tx) * 2 + 1] = s2;
    }
    __syncthreads();
    float g8[8], be8[8];
#pragma unroll
    for (int j = 0; j < 8; j++) { g8[j] = lng[c0 + j]; be8[j] = lnb[c0 + j]; }
#pragma unroll
    for (int i = 0; i < 4; i++) {
        float m1 = 0.f, m2 = 0.f;
        for (int t = 0; t < 16; t++) {
            m1 += AsRed[((r0 + i) * 16 + t) * 2 + 0];
            m2 += AsRed[((r0 + i) * 16 + t) * 2 + 1];
        }
        float mu = m1 * (1.f / 128.f);
        float var = m2 * (1.f / 128.f) - mu * mu;
        float rs = rsqrtf(var + 1e-5f);
        int row = rb + r0 + i;
        if (row < N_NODES) {
            float o[8];
#pragma unroll
            for (int j = 0; j < 8; j++) {
                float v = (vals[i][j] - mu) * rs * g8[j] + be8[j];
                o[j] = v > 0.f ? v : 0.f;
            }
            *(float4*)(xout + (size_t)row * CH + c0) = *(float4*)o;
            *(float4*)(xout + (size_t)row * CH + c0 + 4) = *(float4*)(o + 4);
        }
    }
}

// ---------------- launch ----------------
extern "C" void kernel_launch(void* const* d_in, const int* in_sizes, int n_in,
                              void* d_out, int out_size, void* d_ws, size_t ws_size,
                              hipStream_t stream) {
    const float* fv     = (const float*)d_in[0];
    const int*   adj    = (const int*)d_in[1];
    const float* ev     = (const float*)d_in[2];
    const float* eps    = (const float*)d_in[3];
    const float* edge_W = (const float*)d_in[4];
    const float* edge_b = (const float*)d_in[5];
    const float* W1     = (const float*)d_in[6];
    const float* b1     = (const float*)d_in[7];
    const float* bng    = (const float*)d_in[8];
    const float* bnb    = (const float*)d_in[9];
    const float* bnm    = (const float*)d_in[10];
    const float* bnv    = (const float*)d_in[11];
    const float* W2     = (const float*)d_in[12];
    const float* b2     = (const float*)d_in[13];
    const float* lng    = (const float*)d_in[14];
    const float* lnb    = (const float*)d_in[15];
    float* out = (float*)d_out;

    char* w = (char*)d_ws;
    float* zh = (float*)w;       w += (size_t)N_NODES * CH * sizeof(float);
    float* xA = (float*)w;       w += (size_t)N_NODES * CH * sizeof(float);
    int* deg      = (int*)w;     w += (size_t)N_NODES * sizeof(int);
    int* offs     = (int*)w;     w += (size_t)(N_NODES + 1) * sizeof(int);
    int* cursor   = (int*)w;     w += (size_t)N_NODES * sizeof(int);
    int* blkTot   = (int*)w;     w += 256 * sizeof(int);
    int* blkOff   = (int*)w;     w += 256 * sizeof(int);
    int* slot_eid = (int*)w;     w += (size_t)N_EDGES * sizeof(int);

    // CSR build (per-call; inputs restored before every timed launch)
    hipMemsetAsync(deg, 0, (size_t)N_NODES * sizeof(int), stream);
    k_hist<<<(N_EDGES + 255) / 256, 256, 0, stream>>>(adj + N_EDGES, deg, N_EDGES);
    int nblk = (N_NODES + SCAN_BS - 1) / SCAN_BS;  // 98
    k_scan1<<<nblk, SCAN_BS, 0, stream>>>(deg, blkTot, N_NODES);
    k_scan2<<<1, 128, 0, stream>>>(blkTot, blkOff, nblk);
    k_scan3<<<nblk, SCAN_BS, 0, stream>>>(deg, blkOff, offs, cursor, N_NODES, N_EDGES);
    k_scatter<<<(N_EDGES + 255) / 256, 256, 0, stream>>>(adj, cursor, slot_eid, N_EDGES);

    const float* xin = fv;
    for (int k = 0; k < 3; k++) {
        float* xout = (k == 1) ? xA : out;   // fv -> out -> xA -> out
        k_aggmm<<<N_NODES / NG, 256, 0, stream>>>(
            xin, ev, offs, slot_eid, adj,
            edge_W + (size_t)k * ED * CH, edge_b + (size_t)k * CH, eps + k, zh);
        k_mlp<<<(N_NODES + BM - 1) / BM, 256, 0, stream>>>(
            zh,
            W1 + (size_t)k * CH * CH, b1 + (size_t)k * CH,
            bng + (size_t)k * CH, bnb + (size_t)k * CH,
            bnm + (size_t)k * CH, bnv + (size_t)k * CH,
            W2 + (size_t)k * CH * CH, b2 + (size_t)k * CH,
            lng, lnb, xout);
        xin = xout;
    }
}